// Round 1
// baseline (135.200 us; speedup 1.0000x reference)
//
#include <hip/hip_runtime.h>
#include <hip/hip_bf16.h>
#include <math.h>

#define MC_    10
#define IN_C_  16
#define OUT_C_ 32
#define K_     3
#define D_     (IN_C_ * K_ * K_)   // 144
#define H_     128
#define W_     128
#define HW_    64                  // output spatial (stride 2, pad 1)
#define B_     8

// ---------------------------------------------------------------------------
// Kernel 1: reparameterize weights into d_ws, keeping Omega's native layout
//   W[mc][d][oc] = eps[mc][d][oc] * exp(0.5*logsig[d][oc]) + mean[d][oc]
//   d = (kh*3 + kw)*16 + ic
// ---------------------------------------------------------------------------
__global__ __launch_bounds__(256) void prep_w_kernel(
    const float* __restrict__ eps, const float* __restrict__ logsig,
    const float* __restrict__ mean, float* __restrict__ w)
{
    int i = blockIdx.x * 256 + threadIdx.x;          // over MC*D*OUT_C = 46080
    if (i < MC_ * D_ * OUT_C_) {
        int doc = i % (D_ * OUT_C_);                 // index within one mc
        w[i] = eps[i] * __expf(0.5f * logsig[doc]) + mean[doc];
    }
}

// ---------------------------------------------------------------------------
// Kernel 2: grouped conv (stride 2, pad 1) + RFF cos/sin epilogue.
// grid = (HW_/4, MC_, B_); block = 256 = 4 waves; wave handles one output row
// (lane = ow). Each thread: 1 pixel x 32 oc accumulators; x reused 32x from
// registers, weights are wave-uniform -> scalar loads (SGPR broadcast).
// ---------------------------------------------------------------------------
__global__ __launch_bounds__(256) void conv_rff_kernel(
    const float* __restrict__ x,      // [B][IN_C][128][128]
    const float* __restrict__ w,      // [MC][D][OUT_C] (reparameterized)
    const float* __restrict__ theta,  // [1]
    float* __restrict__ out)          // [B][MC*2*OUT_C][64][64]
{
    const int tid    = threadIdx.x;
    const int lane   = tid & 63;
    const int waveid = tid >> 6;
    const int oh     = blockIdx.x * 4 + waveid;      // 0..63
    const int mc     = blockIdx.y;
    const int b      = blockIdx.z;
    const int ow     = lane;

    const float scale = __expf(0.5f * theta[0]) *
                        rsqrtf((float)(OUT_C_ * HW_ * HW_));

    float acc[OUT_C_];
#pragma unroll
    for (int oc = 0; oc < OUT_C_; ++oc) acc[oc] = 0.0f;

    const float* __restrict__ wmc = w + (size_t)mc * (D_ * OUT_C_);
    const float* __restrict__ xb  = x + (size_t)b * IN_C_ * H_ * W_;
    const int ih0 = oh * 2 - 1;
    const int iw0 = ow * 2 - 1;

    for (int ic = 0; ic < IN_C_; ++ic) {
        const float* __restrict__ xc = xb + (size_t)ic * (H_ * W_);
        float xv[9];
#pragma unroll
        for (int kh = 0; kh < 3; ++kh) {
#pragma unroll
            for (int kw = 0; kw < 3; ++kw) {
                const int ih = ih0 + kh;
                const int iw = iw0 + kw;
                const bool ok = ((unsigned)ih < (unsigned)H_) &&
                                ((unsigned)iw < (unsigned)W_);
                xv[kh * 3 + kw] = ok ? xc[ih * W_ + iw] : 0.0f;
            }
        }
#pragma unroll
        for (int t = 0; t < 9; ++t) {
            // wave-uniform weight address -> s_load into SGPRs
            const float* __restrict__ wp = wmc + (size_t)(t * IN_C_ + ic) * OUT_C_;
            const float xt = xv[t];
#pragma unroll
            for (int oc = 0; oc < OUT_C_; ++oc)
                acc[oc] = fmaf(xt, wp[oc], acc[oc]);
        }
    }

    // epilogue: out[b][mc*64 + oc][oh][ow] = scale*cos, [mc*64+32+oc] = scale*sin
    float* __restrict__ op = out +
        (((size_t)b * (MC_ * 2 * OUT_C_) + (size_t)mc * (2 * OUT_C_)) * (HW_ * HW_)) +
        (size_t)oh * HW_ + ow;
#pragma unroll
    for (int oc = 0; oc < OUT_C_; ++oc) {
        float s, c;
        __sincosf(acc[oc], &s, &c);
        op[(size_t)oc * (HW_ * HW_)]              = scale * c;
        op[(size_t)(oc + OUT_C_) * (HW_ * HW_)]   = scale * s;
    }
}

// ---------------------------------------------------------------------------
extern "C" void kernel_launch(void* const* d_in, const int* in_sizes, int n_in,
                              void* d_out, int out_size, void* d_ws, size_t ws_size,
                              hipStream_t stream)
{
    const float* x      = (const float*)d_in[0];  // (8,16,128,128)
    const float* theta  = (const float*)d_in[1];  // (1,)
    const float* mean   = (const float*)d_in[2];  // (144,32)
    const float* logsig = (const float*)d_in[3];  // (144,32)
    const float* eps    = (const float*)d_in[4];  // (10,144,32)
    float* out = (float*)d_out;
    float* W   = (float*)d_ws;                    // 46080 floats = 184 KB

    const int n_w = MC_ * D_ * OUT_C_;
    prep_w_kernel<<<(n_w + 255) / 256, 256, 0, stream>>>(eps, logsig, mean, W);

    dim3 grid(HW_ / 4, MC_, B_);                  // (16, 10, 8)
    conv_rff_kernel<<<grid, 256, 0, stream>>>(x, W, theta, out);
}

// Round 2
// 118.198 us; speedup vs baseline: 1.1438x; 1.1438x over previous
//
#include <hip/hip_runtime.h>
#include <hip/hip_bf16.h>
#include <math.h>

#define MC_    10
#define IN_C_  16
#define OUT_C_ 32
#define K_     3
#define D_     144
#define KP_    160                 // K padded to 5 x 32
#define H_     128
#define W_     128
#define HW_    64
#define B_     8

typedef __attribute__((ext_vector_type(8))) short short8;   // 8 bf16 = 4 VGPR
typedef __attribute__((ext_vector_type(4))) float f32x4;

static __device__ __forceinline__ unsigned short f2bf(float v) {
    union { float f; unsigned u; } x; x.f = v;
    unsigned r = x.u + 0x7fff + ((x.u >> 16) & 1);           // RNE
    return (unsigned short)(r >> 16);
}

// ---------------------------------------------------------------------------
// Kernel 1: reparameterize + transpose + bf16-cast weights into d_ws:
//   W2[mc][oc][k] (k padded to 160, zeros for k>=144), k = (kh*3+kw)*16+ic = d
// ---------------------------------------------------------------------------
__global__ __launch_bounds__(256) void prep_w_kernel(
    const float* __restrict__ eps, const float* __restrict__ logsig,
    const float* __restrict__ mean, unsigned short* __restrict__ w2)
{
    int i = blockIdx.x * 256 + threadIdx.x;      // over 10*32*160 = 51200
    if (i >= MC_ * OUT_C_ * KP_) return;
    int k  = i % KP_;
    int oc = (i / KP_) % OUT_C_;
    int mc = i / (KP_ * OUT_C_);
    float val = 0.0f;
    if (k < D_) {
        int doc = k * OUT_C_ + oc;
        val = eps[mc * (D_ * OUT_C_) + doc] * __expf(0.5f * logsig[doc]) + mean[doc];
    }
    w2[i] = f2bf(val);
}

// ---------------------------------------------------------------------------
// Kernel 2: implicit-GEMM conv via bf16 MFMA + RFF epilogue.
// grid = (128 m-tiles, 8 b); block = 256 = 4 waves (2m x 2n).
// Tile: 32 pixels (one oh, half an output row) x 32 oc, all 10 mc.
// A (im2col, bf16, K=160) built once in LDS, reused across mc.
// B loaded straight from global (L1-resident 10 KB per mc).
// ---------------------------------------------------------------------------
__global__ __launch_bounds__(256) void conv_rff_mfma(
    const float* __restrict__ x,              // [B][16][128][128]
    const unsigned short* __restrict__ w2,    // [MC][32][160] bf16
    const float* __restrict__ theta,
    float* __restrict__ out)                  // [B][640][64][64]
{
    __shared__ __align__(16) unsigned short Alds[32 * 168];  // stride 168 bf16
    __shared__ __align__(16) float Clds[32 * 36];            // [oc][m], stride 36

    const int tid  = threadIdx.x;
    const int tile = blockIdx.x;              // 0..127
    const int b    = blockIdx.y;
    const int oh   = tile >> 1;
    const int ow0  = (tile & 1) << 5;
    const float* __restrict__ xb = x + (size_t)b * (IN_C_ * H_ * W_);

    // ---- im2col: A[m=0..31][k=0..159] ----
#pragma unroll
    for (int j = 0; j < 20; ++j) {
        int idx = j * 256 + tid;              // 0..5119
        int m = idx & 31;
        int k = idx >> 5;                     // 0..159
        float val = 0.0f;
        if (k < D_) {
            int ic = k & 15;
            int t  = k >> 4;                  // 0..8
            int kh = (t * 11) >> 5;           // t/3
            int kw = t - kh * 3;
            int ih = oh * 2 - 1 + kh;
            int iw = (ow0 + m) * 2 - 1 + kw;
            if ((unsigned)ih < (unsigned)H_ && (unsigned)iw < (unsigned)W_)
                val = xb[ic * (H_ * W_) + ih * W_ + iw];
        }
        Alds[m * 168 + k] = f2bf(val);
    }
    __syncthreads();

    const int lane = tid & 63;
    const int wave = tid >> 6;
    const int wm   = (wave >> 1) << 4;        // pixel offset: 0 / 16
    const int wn   = (wave & 1) << 4;         // oc offset:    0 / 16
    const int l15  = lane & 15;
    const int quad = lane >> 4;

    // A-fragments for all 5 K-steps, kept in registers across the mc loop.
    // A-layout: lane holds A[m = l15][k = quad*8 + j]  (m120-verified)
    short8 af[5];
#pragma unroll
    for (int ks = 0; ks < 5; ++ks)
        af[ks] = *(const short8*)&Alds[(wm + l15) * 168 + ks * 32 + quad * 8];

    const float scale = __expf(0.5f * theta[0]) * rsqrtf((float)(OUT_C_ * HW_ * HW_));

    const int  rid    = tid >> 2;             // 0..63: output channel row
    const int  q      = tid & 3;              // ow chunk of 8
    const int  ocr    = rid & 31;
    const bool is_cos = rid < 32;             // wave-uniform

    float* __restrict__ outb =
        out + (size_t)b * (MC_ * 2 * OUT_C_ * HW_ * HW_) + oh * HW_ + ow0;

    for (int mc = 0; mc < MC_; ++mc) {
        // B-fragments: lane holds B[k = quad*8 + j][n = l15] from W2[oc][k]
        const unsigned short* __restrict__ wmc = w2 + (size_t)mc * (OUT_C_ * KP_);
        short8 bfr[5];
#pragma unroll
        for (int ks = 0; ks < 5; ++ks)
            bfr[ks] = *(const short8*)&wmc[(wn + l15) * KP_ + ks * 32 + quad * 8];

        f32x4 acc = {0.f, 0.f, 0.f, 0.f};
#pragma unroll
        for (int ks = 0; ks < 5; ++ks)
            acc = __builtin_amdgcn_mfma_f32_16x16x32_bf16(af[ks], bfr[ks], acc, 0, 0, 0);

        __syncthreads();                      // Clds safe to overwrite
        // C-layout: col(oc) = l15, row(m) = quad*4 + r  (m89/m91-verified)
#pragma unroll
        for (int r = 0; r < 4; ++r)
            Clds[(wn + l15) * 36 + wm + quad * 4 + r] = acc[r];
        __syncthreads();

        // coalesced epilogue: row rid -> channel mc*64+rid (cos | sin)
        float4 p0 = *(const float4*)&Clds[ocr * 36 + q * 8];
        float4 p1 = *(const float4*)&Clds[ocr * 36 + q * 8 + 4];
        float v[8];
        float ph[8] = {p0.x, p0.y, p0.z, p0.w, p1.x, p1.y, p1.z, p1.w};
#pragma unroll
        for (int i = 0; i < 8; ++i)
            v[i] = scale * (is_cos ? __cosf(ph[i]) : __sinf(ph[i]));
        float* __restrict__ po = outb + (size_t)(mc * 64 + rid) * (HW_ * HW_) + q * 8;
        *(float4*)po       = make_float4(v[0], v[1], v[2], v[3]);
        *((float4*)po + 1) = make_float4(v[4], v[5], v[6], v[7]);
    }
}

// ---------------------------------------------------------------------------
extern "C" void kernel_launch(void* const* d_in, const int* in_sizes, int n_in,
                              void* d_out, int out_size, void* d_ws, size_t ws_size,
                              hipStream_t stream)
{
    const float* x      = (const float*)d_in[0];  // (8,16,128,128)
    const float* theta  = (const float*)d_in[1];  // (1,)
    const float* mean   = (const float*)d_in[2];  // (144,32)
    const float* logsig = (const float*)d_in[3];  // (144,32)
    const float* eps    = (const float*)d_in[4];  // (10,144,32)
    float* out = (float*)d_out;
    unsigned short* W2 = (unsigned short*)d_ws;   // 51200 bf16 = 100 KB

    const int n_w = MC_ * OUT_C_ * KP_;           // 51200
    prep_w_kernel<<<(n_w + 255) / 256, 256, 0, stream>>>(eps, logsig, mean, W2);

    dim3 grid(128, B_);                           // 1024 blocks
    conv_rff_mfma<<<grid, 256, 0, stream>>>(x, W2, theta, out);
}

// Round 4
// 112.632 us; speedup vs baseline: 1.2004x; 1.0494x over previous
//
#include <hip/hip_runtime.h>
#include <hip/hip_bf16.h>
#include <math.h>

#define MC_    10
#define IN_C_  16
#define OUT_C_ 32
#define K_     3
#define D_     144
#define KP_    160                 // K padded to 5 x 32
#define H_     128
#define W_     128
#define HW_    64
#define B_     8

typedef __attribute__((ext_vector_type(8))) short short8;   // 8 bf16 = 4 VGPR
typedef __attribute__((ext_vector_type(4))) float f32x4;

static __device__ __forceinline__ unsigned short f2bf(float v) {
    union { float f; unsigned u; } x; x.f = v;
    unsigned r = x.u + 0x7fff + ((x.u >> 16) & 1);           // RNE
    return (unsigned short)(r >> 16);
}

// ---------------------------------------------------------------------------
// Kernel 1: reparameterize + transpose + bf16-cast weights into d_ws:
//   W2[mc][oc][k] (k padded to 160, zeros for k>=144), k = (kh*3+kw)*16+ic = d
// ---------------------------------------------------------------------------
__global__ __launch_bounds__(256) void prep_w_kernel(
    const float* __restrict__ eps, const float* __restrict__ logsig,
    const float* __restrict__ mean, unsigned short* __restrict__ w2)
{
    int i = blockIdx.x * 256 + threadIdx.x;      // over 10*32*160 = 51200
    if (i >= MC_ * OUT_C_ * KP_) return;
    int k  = i % KP_;
    int oc = (i / KP_) % OUT_C_;
    int mc = i / (KP_ * OUT_C_);
    float val = 0.0f;
    if (k < D_) {
        int doc = k * OUT_C_ + oc;
        val = eps[mc * (D_ * OUT_C_) + doc] * __expf(0.5f * logsig[doc]) + mean[doc];
    }
    w2[i] = f2bf(val);
}

// ---------------------------------------------------------------------------
// Kernel 2: implicit-GEMM conv via bf16 MFMA + RFF epilogue.
// grid = (128 m-tiles, 8 b); block = 256 = 4 waves (2 oc-tiles x 2 px-tiles).
// Tile: 32 pixels (one oh, half an output row) x 32 oc, all 10 mc.
// Weights are the MFMA *A* operand, pixels are *B*: C comes out as
// [oc][pixel] -> col(lane&15)=pixel, so stores are direct 64B-coalesced
// from the accumulator. No C transpose, no barriers in the mc loop.
// ---------------------------------------------------------------------------
__global__ __launch_bounds__(256) void conv_rff_mfma(
    const float* __restrict__ x,              // [B][16][128][128]
    const unsigned short* __restrict__ w2,    // [MC][32][160] bf16
    const float* __restrict__ theta,
    float* __restrict__ out)                  // [B][640][64][64]
{
    __shared__ __align__(16) unsigned short Alds[32 * 168];  // im2col, stride 168

    const int tid  = threadIdx.x;
    const int tile = blockIdx.x;              // 0..127
    const int b    = blockIdx.y;
    const int oh   = tile >> 1;
    const int ow0  = (tile & 1) << 5;
    const float* __restrict__ xb = x + (size_t)b * (IN_C_ * H_ * W_);

    // ---- im2col: A[px=0..31][k=0..159] ----
#pragma unroll
    for (int j = 0; j < 20; ++j) {
        int idx = j * 256 + tid;              // 0..5119
        int m = idx & 31;
        int k = idx >> 5;                     // 0..159
        float val = 0.0f;
        if (k < D_) {
            int ic = k & 15;
            int t  = k >> 4;                  // 0..8
            int kh = (t * 11) >> 5;           // t/3
            int kw = t - kh * 3;
            int ih = oh * 2 - 1 + kh;
            int iw = (ow0 + m) * 2 - 1 + kw;
            if ((unsigned)ih < (unsigned)H_ && (unsigned)iw < (unsigned)W_)
                val = xb[ic * (H_ * W_) + ih * W_ + iw];
        }
        Alds[m * 168 + k] = f2bf(val);
    }
    __syncthreads();

    const int lane  = tid & 63;
    const int wave  = tid >> 6;
    const int wn_oc = (wave & 1) << 4;        // oc-tile offset:    0 / 16
    const int wm_px = (wave >> 1) << 4;       // pixel-tile offset: 0 / 16
    const int l15   = lane & 15;
    const int quad  = lane >> 4;

    // Pixel (B) fragments for all 5 K-steps, registers across the mc loop.
    // B-layout: lane holds B[k = quad*8 + j][n = l15]  <=>  im2col[px][k]
    short8 pf[5];
#pragma unroll
    for (int ks = 0; ks < 5; ++ks)
        pf[ks] = *(const short8*)&Alds[(wm_px + l15) * 168 + ks * 32 + quad * 8];

    const float scale = __expf(0.5f * theta[0]) * rsqrtf((float)(OUT_C_ * HW_ * HW_));

    // out[b][ch][oh][ow0 + wm_px + px]; per-quad 16 lanes -> 64B segments.
    // R3 bug was the missing wm_px here (waves 2/3 stomped pixels 0-15).
    float* __restrict__ po =
        out + (size_t)b * (MC_ * 2 * OUT_C_ * HW_ * HW_) + oh * HW_ + ow0 + wm_px + l15;

    for (int mc = 0; mc < MC_; ++mc) {
        // Weight (A) fragments: lane holds A[m = l15][k = quad*8 + j] = W2[oc][k]
        const unsigned short* __restrict__ wmc = w2 + (size_t)mc * (OUT_C_ * KP_);
        short8 wf[5];
#pragma unroll
        for (int ks = 0; ks < 5; ++ks)
            wf[ks] = *(const short8*)&wmc[(wn_oc + l15) * KP_ + ks * 32 + quad * 8];

        f32x4 acc = {0.f, 0.f, 0.f, 0.f};
#pragma unroll
        for (int ks = 0; ks < 5; ++ks)
            acc = __builtin_amdgcn_mfma_f32_16x16x32_bf16(wf[ks], pf[ks], acc, 0, 0, 0);

        // C layout: col = l15 = pixel, row = quad*4 + r = oc (16x16 tile)
        const int ch0 = mc * (2 * OUT_C_) + wn_oc + quad * 4;   // cos channels
#pragma unroll
        for (int r = 0; r < 4; ++r) {
            float s, c;
            __sincosf(acc[r], &s, &c);
            po[(size_t)(ch0 + r) * (HW_ * HW_)]           = scale * c;
            po[(size_t)(ch0 + r + OUT_C_) * (HW_ * HW_)]  = scale * s;
        }
    }
}

// ---------------------------------------------------------------------------
extern "C" void kernel_launch(void* const* d_in, const int* in_sizes, int n_in,
                              void* d_out, int out_size, void* d_ws, size_t ws_size,
                              hipStream_t stream)
{
    const float* x      = (const float*)d_in[0];  // (8,16,128,128)
    const float* theta  = (const float*)d_in[1];  // (1,)
    const float* mean   = (const float*)d_in[2];  // (144,32)
    const float* logsig = (const float*)d_in[3];  // (144,32)
    const float* eps    = (const float*)d_in[4];  // (10,144,32)
    float* out = (float*)d_out;
    unsigned short* W2 = (unsigned short*)d_ws;   // 51200 bf16 = 100 KB

    const int n_w = MC_ * OUT_C_ * KP_;           // 51200
    prep_w_kernel<<<(n_w + 255) / 256, 256, 0, stream>>>(eps, logsig, mean, W2);

    dim3 grid(128, B_);                           // 1024 blocks
    conv_rff_mfma<<<grid, 256, 0, stream>>>(x, W2, theta, out);
}